// Round 4
// baseline (420.843 us; speedup 1.0000x reference)
//
#include <hip/hip_runtime.h>
#include <math.h>

#define NN 30000
#define BB 16
#define NBLK 118
#define DIST_C 5.0f
#define EPS_C 1e-6f
#define SCALE_C 0.17677669529663687f  // 1/sqrt(32)

// workspace layout (float offsets)
#define WS_BAR  0      // 8 uints: [0] = monotonic barrier counter (memset 0)
#define WS_PZM  8      // 16*128 uints [b*128+blk]: per-block max(fencode(-z))
#define WS_PZX  2056   // 16*128 uints [b*128+blk]: per-block max(fencode(z))
#define WS_ZSUM 4104   // 32 f [b*2+s]          (zeroed in-kernel)
#define WS_T    4136   // 8192 f [b*512+(s*8+h)*32+d] (zeroed in-kernel)
#define WS_AKG  12328  // 8192 f [b*512+s*256+h*32+e]
#define WS_AVG  20520  // 8192 f

// LDS row strides (conflict-free; see round-1 analysis)
#define LWS 17
#define LFS 36

__device__ __forceinline__ unsigned fencode(float f) {
    unsigned u = __float_as_uint(f);
    return (u & 0x80000000u) ? ~u : (u | 0x80000000u);
}
__device__ __forceinline__ float fdecode(unsigned c) {
    return __uint_as_float((c & 0x80000000u) ? (c ^ 0x80000000u) : ~c);
}
__device__ __forceinline__ float silu(float x) { return x / (1.0f + expf(-x)); }

// Device-scope grid barrier: monotonic counter, no reset. All NBLK blocks are
// co-resident by construction (118 blocks, 256 CUs, <=1 block/CU demand), so
// spinning cannot deadlock. Release: __syncthreads drains each wave's vmcnt,
// then thread 0's __threadfence (agent release) writes back L2; acquire-load
// on the spin invalidates stale lines for the whole CU/XCD.
__device__ __forceinline__ void gbarrier(unsigned* cnt, unsigned target) {
    __syncthreads();
    if (threadIdx.x == 0) {
        __threadfence();
        __hip_atomic_fetch_add(cnt, 1u, __ATOMIC_ACQ_REL, __HIP_MEMORY_SCOPE_AGENT);
        while (__hip_atomic_load(cnt, __ATOMIC_ACQUIRE, __HIP_MEMORY_SCOPE_AGENT) < target) {
            __builtin_amdgcn_s_sleep(2);
        }
    }
    __syncthreads();
}

__global__ __launch_bounds__(256) void k_fused(
    const float* __restrict__ pos, const int* __restrict__ batch,
    const float* __restrict__ nf, const float* __restrict__ bw,
    const float* __restrict__ init_dummy, const float* __restrict__ Wq_dummy,
    const float* __restrict__ Wq_graph, const float* __restrict__ Wdot,
    const float* __restrict__ W1_kd, const float* __restrict__ W2_kd,
    const float* __restrict__ W1_vd, const float* __restrict__ W2_vd,
    const float* __restrict__ W1_kg, const float* __restrict__ W2_kg,
    const float* __restrict__ W1_vg, const float* __restrict__ W2_vg,
    float* __restrict__ ws, float* __restrict__ out)
{
    __shared__ float Lw[256 * LWS];
    __shared__ float Lf[256 * LFS];
    __shared__ int   Lb[256];
    __shared__ float W1kd[64], W1vd[64], W1kg[64], W1vg[64];
    __shared__ float Pk[256], Wc[1024], qv[64], zsl[32], bwl[8];
    __shared__ unsigned zl[16], zh[16];

    int t = threadIdx.x;
    unsigned* wsu = (unsigned*)ws;
    unsigned* barc = wsu + WS_BAR;

    // ================= step 0: staging, precompute, partial z, zero T ======
    if (t < 64) { W1kd[t] = W1_kd[t]; W1vd[t] = W1_vd[t];
                  W1kg[t] = W1_kg[t]; W1vg[t] = W1_vg[t]; }
    if (t < 8)  bwl[t] = bw[t];
    if (t < 16) { zl[t] = 0u; zh[t] = 0u; }
    if (t < 32) zsl[t] = 0.0f;
    if (t < 32) {                       // qvec = init_dummy @ Wq_dummy
        float acc = 0.0f;
        for (int d = 0; d < 32; ++d) acc += init_dummy[d] * Wq_dummy[d * 32 + t];
        qv[t] = acc;
    }
    __syncthreads();
    if (t < 32) {                       // qW = qvec @ Wdot
        float acc = 0.0f;
        for (int e = 0; e < 32; ++e) acc += qv[e] * Wdot[e * 32 + t];
        qv[32 + t] = acc;
    }

    int n = blockIdx.x * 256 + t;
    bool act = n < NN;
    float z = 0.0f; int b = 0;
    float f[32]; float4 fv4[8];
    #pragma unroll
    for (int j = 0; j < 8; ++j) { fv4[j].x = fv4[j].y = fv4[j].z = fv4[j].w = 0.0f; }
    if (act) {
        z = pos[3 * n + 2];
        b = batch[n];
        const float4* nf4 = (const float4*)nf;
        float4* Lf4 = (float4*)Lf;
        #pragma unroll
        for (int j = 0; j < 8; ++j) {
            float4 v = nf4[n * 8 + j];
            fv4[j] = v;
            f[4*j] = v.x; f[4*j+1] = v.y; f[4*j+2] = v.z; f[4*j+3] = v.w;
            Lf4[t * 9 + j] = v;
        }
        atomicMax(&zl[b], fencode(-z));   // max fencode(-z) = fencode(-zmin)
        atomicMax(&zh[b], fencode(z));    // max fencode(z)  = fencode(zmax)
        Lb[t] = b;
    } else {
        #pragma unroll
        for (int j = 0; j < 32; ++j) f[j] = 0.0f;
        Lb[t] = -1;
    }
    __syncthreads();                    // qv[32..], zl/zh block-partials ready
    {   // Pk[h][d] = sum_e W2_kd[h,d*32+e] * qW[e]
        int h = t >> 5, d = t & 31;
        float acc = 0.0f;
        for (int e = 0; e < 32; ++e) acc += W2_kd[h * 1024 + d * 32 + e] * qv[32 + e];
        Pk[t] = acc;
    }
    for (int i = t; i < 1024; i += 256) {   // Wc = Wq_graph @ Wdot
        int d = i >> 5, e = i & 31;
        float acc = 0.0f;
        for (int m = 0; m < 32; ++m) acc += Wq_graph[d * 32 + m] * Wdot[m * 32 + e];
        Wc[i] = acc;
    }
    if (t < 16) {                       // publish partials, reset for reuse
        wsu[WS_PZM + t * 128 + blockIdx.x] = zl[t];
        wsu[WS_PZX + t * 128 + blockIdx.x] = zh[t];
        zl[t] = 0u; zh[t] = 0u;
    }
    {   // zero ZSUM + T  (floats [WS_ZSUM, WS_T+8192) = 8224 elements)
        int g = blockIdx.x * 256 + t;
        if (g < 8224) ws[WS_ZSUM + g] = 0.0f;
    }
    gbarrier(barc, NBLK);               // ---- partials + zeroed T everywhere

    // ================= step A: z-reduce, edges, activations, qgW, T =======
    {   // reduce 118 partials per batch: thread t -> (batch t>>4, chunk t&15)
        int b4 = t >> 4, c = t & 15;
        unsigned m0 = 0u, m1 = 0u;
        int i0 = c * 8, i1 = i0 + 8; if (i1 > NBLK) i1 = NBLK;
        for (int i = i0; i < i1; ++i) {
            unsigned p0 = wsu[WS_PZM + b4 * 128 + i];
            unsigned p1 = wsu[WS_PZX + b4 * 128 + i];
            m0 = m0 > p0 ? m0 : p0;
            m1 = m1 > p1 ? m1 : p1;
        }
        atomicMax(&zl[b4], m0);
        atomicMax(&zh[b4], m1);
    }
    __syncthreads();

    float akg[2][8], avgg[2][8];
    float4 q4[8];
    #pragma unroll
    for (int j = 0; j < 8; ++j) { q4[j].x = q4[j].y = q4[j].z = q4[j].w = 0.0f; }
    {
        float zmin = -fdecode(zl[b]);
        float zmax =  fdecode(zh[b]);
        float xl[2];
        xl[0] = z - zmin + DIST_C;
        xl[1] = zmax + DIST_C - z;
        float edge[2][8];
        #pragma unroll
        for (int s = 0; s < 2; ++s) {
            float inv = 1.0f / (xl[s] + EPS_C);
            #pragma unroll
            for (int k = 0; k < 8; ++k) edge[s][k] = sinf(bwl[k] * xl[s]) * inv;
        }
        float u[8];
        #pragma unroll
        for (int h = 0; h < 8; ++h) {
            float acc = 0.0f;
            #pragma unroll
            for (int d = 0; d < 32; ++d) acc += f[d] * Pk[h * 32 + d];
            u[h] = acc;
        }
        #pragma unroll
        for (int s = 0; s < 2; ++s) {
            float sacc = 0.0f;
            #pragma unroll
            for (int h = 0; h < 8; ++h) {
                float pkd = 0.0f, pvd = 0.0f, pkg = 0.0f, pvg = 0.0f;
                #pragma unroll
                for (int k = 0; k < 8; ++k) {
                    float e8 = edge[s][k];
                    pkd += e8 * W1kd[k * 8 + h];
                    pvd += e8 * W1vd[k * 8 + h];
                    pkg += e8 * W1kg[k * 8 + h];
                    pvg += e8 * W1vg[k * 8 + h];
                }
                sacc += silu(pkd) * u[h];
                Lw[t * LWS + s * 8 + h] = silu(pvd);
                akg[s][h] = silu(pkg);
                avgg[s][h] = silu(pvg);
            }
            float ev = act ? expf(sacc * SCALE_C) : 0.0f;
            if (act) atomicAdd(&zsl[b * 2 + s], ev);
            #pragma unroll
            for (int h = 0; h < 8; ++h) Lw[t * LWS + s * 8 + h] *= ev;
        }
        // qgW = f @ Wc
        const float4* Wc4 = (const float4*)Wc;
        #pragma unroll
        for (int d = 0; d < 32; ++d) {
            float fd = f[d];
            #pragma unroll
            for (int j = 0; j < 8; ++j) {
                float4 w = Wc4[d * 8 + j];
                q4[j].x += fd * w.x; q4[j].y += fd * w.y;
                q4[j].z += fd * w.z; q4[j].w += fd * w.w;
            }
        }
    }
    __syncthreads();                    // Lw, zsl complete
    if (t < 32 && zsl[t] != 0.0f) atomicAdd(&ws[WS_ZSUM + t], zsl[t]);

    {   // segment outer-product reduce: T[b] += W^T(16 x n) @ F(n x 32)
        int base = blockIdx.x * 256;
        int count = NN - base; if (count > 256) count = 256;
        int bf = Lb[0], bl = Lb[count - 1];
        int wave = t >> 6, lane = t & 63;
        int sh = lane & 15;
        int dg = lane >> 4;
        int i0 = wave * 64;
        int i1 = i0 + 64; if (i1 > count) i1 = count;
        const float4* Lf4r = (const float4*)Lf;
        for (int b2 = bf; b2 <= bl; ++b2) {
            float a0=0.f,a1=0.f,a2=0.f,a3=0.f,a4=0.f,a5=0.f,a6=0.f,a7=0.f;
            for (int i = i0; i < i1; ++i) {
                if (Lb[i] != b2) continue;
                float w = Lw[i * LWS + sh];
                float4 x0 = Lf4r[i * 9 + 2 * dg];
                float4 x1 = Lf4r[i * 9 + 2 * dg + 1];
                a0 += w * x0.x; a1 += w * x0.y; a2 += w * x0.z; a3 += w * x0.w;
                a4 += w * x1.x; a5 += w * x1.y; a6 += w * x1.z; a7 += w * x1.w;
            }
            float* Tb = ws + WS_T + b2 * 512 + sh * 32 + dg * 8;
            atomicAdd(&Tb[0], a0); atomicAdd(&Tb[1], a1);
            atomicAdd(&Tb[2], a2); atomicAdd(&Tb[3], a3);
            atomicAdd(&Tb[4], a4); atomicAdd(&Tb[5], a5);
            atomicAdd(&Tb[6], a6); atomicAdd(&Tb[7], a7);
        }
    }
    gbarrier(barc, 2 * NBLK);           // ---- T, zsum final everywhere ----

    // ================= step B: blocks 0..31 build dummy_new, A_kg, A_vg ===
    if (blockIdx.x < 32) {
        int b3 = blockIdx.x >> 1, s3 = blockIdx.x & 1;
        float* Tl = Lf;                 // Lf is dead; reuse
        float* dn = Lf + 320;
        Tl[t] = ws[WS_T + b3 * 512 + s3 * 256 + t];
        __syncthreads();
        if (t < 32) {
            float acc = 0.0f;
            #pragma unroll
            for (int h = 0; h < 8; ++h)
                #pragma unroll
                for (int d = 0; d < 32; ++d)
                    acc += Tl[h * 32 + d] * W2_vd[h * 1024 + d * 32 + t];
            float zs = ws[WS_ZSUM + b3 * 2 + s3];
            dn[t] = init_dummy[t] + acc / zs;
        }
        __syncthreads();
        {
            int h = t >> 5, e = t & 31;
            float ak = 0.0f, av = 0.0f;
            #pragma unroll
            for (int d = 0; d < 32; ++d) {
                float dv = dn[d];
                ak += dv * W2_kg[h * 1024 + d * 32 + e];
                av += dv * W2_vg[h * 1024 + d * 32 + e];
            }
            ws[WS_AKG + b3 * 512 + s3 * 256 + t] = ak;
            ws[WS_AVG + b3 * 512 + s3 * 256 + t] = av;
        }
    }
    gbarrier(barc, 3 * NBLK);           // ---- A_kg / A_vg visible ----

    // ================= step C: finale ====================================
    if (act) {
        const float4* Ak4 = (const float4*)(ws + WS_AKG);
        const float4* Av4 = (const float4*)(ws + WS_AVG);
        float sg[2];
        #pragma unroll
        for (int s = 0; s < 2; ++s) {
            float acc = 0.0f;
            #pragma unroll
            for (int h = 0; h < 8; ++h) {
                int rb = b * 128 + s * 64 + h * 8;
                float dotv = 0.0f;
                #pragma unroll
                for (int j = 0; j < 8; ++j) {
                    float4 a = Ak4[rb + j];
                    dotv += q4[j].x * a.x + q4[j].y * a.y + q4[j].z * a.z + q4[j].w * a.w;
                }
                acc += akg[s][h] * dotv;
            }
            sg[s] = acc * SCALE_C;
        }
        float mm = fmaxf(sg[0], sg[1]);
        float e0 = expf(sg[0] - mm), e1 = expf(sg[1] - mm);
        float inv = 1.0f / (e0 + e1);
        float ag0 = e0 * inv, ag1 = e1 * inv;
        float4 x4[8];
        #pragma unroll
        for (int j = 0; j < 8; ++j) x4[j] = fv4[j];
        #pragma unroll
        for (int s = 0; s < 2; ++s) {
            float ags = (s == 0) ? ag0 : ag1;
            #pragma unroll
            for (int h = 0; h < 8; ++h) {
                float wv = ags * avgg[s][h];
                int rb = b * 128 + s * 64 + h * 8;
                #pragma unroll
                for (int j = 0; j < 8; ++j) {
                    float4 a = Av4[rb + j];
                    x4[j].x += wv * a.x; x4[j].y += wv * a.y;
                    x4[j].z += wv * a.z; x4[j].w += wv * a.w;
                }
            }
        }
        float4* out4 = (float4*)out;
        #pragma unroll
        for (int j = 0; j < 8; ++j) out4[n * 8 + j] = x4[j];
    }
}

extern "C" void kernel_launch(void* const* d_in, const int* in_sizes, int n_in,
                              void* d_out, int out_size, void* d_ws, size_t ws_size,
                              hipStream_t stream) {
    const float* pos        = (const float*)d_in[0];
    const float* nf         = (const float*)d_in[1];
    const int*   batch      = (const int*)d_in[2];
    const float* bw         = (const float*)d_in[3];
    const float* init_dummy = (const float*)d_in[4];
    const float* Wq_dummy   = (const float*)d_in[5];
    const float* Wq_graph   = (const float*)d_in[6];
    const float* Wdot       = (const float*)d_in[7];
    const float* W1_kd      = (const float*)d_in[8];
    const float* W2_kd      = (const float*)d_in[9];
    const float* W1_vd      = (const float*)d_in[10];
    const float* W2_vd      = (const float*)d_in[11];
    const float* W1_kg      = (const float*)d_in[12];
    const float* W2_kg      = (const float*)d_in[13];
    const float* W1_vg      = (const float*)d_in[14];
    const float* W2_vg      = (const float*)d_in[15];
    float* ws  = (float*)d_ws;
    float* out = (float*)d_out;

    // zero the barrier counter (everything else is initialized in-kernel)
    hipMemsetAsync(d_ws, 0x00, 32, stream);

    hipLaunchKernelGGL(k_fused, dim3(NBLK), dim3(256), 0, stream,
                       pos, batch, nf, bw, init_dummy, Wq_dummy, Wq_graph,
                       Wdot, W1_kd, W2_kd, W1_vd, W2_vd, W1_kg, W2_kg,
                       W1_vg, W2_vg, ws, out);
}

// Round 5
// 161.140 us; speedup vs baseline: 2.6117x; 2.6117x over previous
//
#include <hip/hip_runtime.h>
#include <math.h>

#define NN 30000
#define BB 16
#define NBLK 118
#define DIST_C 5.0f
#define EPS_C 1e-6f
#define SCALE_C 0.17677669529663687f  // 1/sqrt(32)

// workspace layout (float offsets)
#define WS_BAR  0      // 8 uints: [0] = monotonic barrier counter (memset 0)
#define WS_PZM  8      // 16*128 uints [b*128+blk]: per-block max(fencode(-z))
#define WS_PZX  2056   // 16*128 uints [b*128+blk]: per-block max(fencode(z))
#define WS_ZSUM 4104   // 32 f [b*2+s]          (zeroed in-kernel)
#define WS_T    4136   // 8192 f [b*512+(s*8+h)*32+d] (zeroed in-kernel)
#define WS_AKG  12328  // 8192 f [b*512+s*256+h*32+e]
#define WS_AVG  20520  // 8192 f

// LDS row strides (conflict-free; see round-1 analysis)
#define LWS 17
#define LFS 36

__device__ __forceinline__ unsigned fencode(float f) {
    unsigned u = __float_as_uint(f);
    return (u & 0x80000000u) ? ~u : (u | 0x80000000u);
}
__device__ __forceinline__ float fdecode(unsigned c) {
    return __uint_as_float((c & 0x80000000u) ? (c ^ 0x80000000u) : ~c);
}
__device__ __forceinline__ float silu(float x) { return x / (1.0f + expf(-x)); }

// Device-scope grid barrier: monotonic counter, no reset. All NBLK blocks are
// co-resident by construction (118 blocks <= 256 CUs at 1 block/CU demand),
// so spinning cannot deadlock.
__device__ __forceinline__ void gbarrier(unsigned* cnt, unsigned target) {
    __syncthreads();
    if (threadIdx.x == 0) {
        __threadfence();
        __hip_atomic_fetch_add(cnt, 1u, __ATOMIC_ACQ_REL, __HIP_MEMORY_SCOPE_AGENT);
        while (__hip_atomic_load(cnt, __ATOMIC_ACQUIRE, __HIP_MEMORY_SCOPE_AGENT) < target) {
            __builtin_amdgcn_s_sleep(2);
        }
    }
    __syncthreads();
}

__global__ __launch_bounds__(256) void k_fused(
    const float* __restrict__ pos, const int* __restrict__ batch,
    const float* __restrict__ nf, const float* __restrict__ bw,
    const float* __restrict__ init_dummy, const float* __restrict__ Wq_dummy,
    const float* __restrict__ Wq_graph, const float* __restrict__ Wdot,
    const float* __restrict__ W1_kd, const float* __restrict__ W2_kd,
    const float* __restrict__ W1_vd, const float* __restrict__ W2_vd,
    const float* __restrict__ W1_kg, const float* __restrict__ W2_kg,
    const float* __restrict__ W1_vg, const float* __restrict__ W2_vg,
    float* __restrict__ ws, float* __restrict__ out)
{
    __shared__ float Lw[256 * LWS];       // step A: weights; step B: scratch
    __shared__ float Lf[256 * LFS];       // node features (persist to step C)
    __shared__ int   Lb[256];
    __shared__ float W1kd[64], W1vd[64], W1kg[64], W1vg[64];
    __shared__ float Pk[256], Wc[1024], qv[64], zsl[32], bwl[8];
    __shared__ unsigned zl[16], zh[16];   // persist to step C

    int t = threadIdx.x;
    unsigned* wsu = (unsigned*)ws;
    unsigned* barc = wsu + WS_BAR;

    // ====== step 0: staging, precompute, z partials, zero T, u = f.Pk ======
    if (t < 64) { W1kd[t] = W1_kd[t]; W1vd[t] = W1_vd[t];
                  W1kg[t] = W1_kg[t]; W1vg[t] = W1_vg[t]; }
    if (t < 8)  bwl[t] = bw[t];
    if (t < 16) { zl[t] = 0u; zh[t] = 0u; }
    if (t < 32) zsl[t] = 0.0f;
    if (t < 32) {                       // qvec = init_dummy @ Wq_dummy
        float acc = 0.0f;
        for (int d = 0; d < 32; ++d) acc += init_dummy[d] * Wq_dummy[d * 32 + t];
        qv[t] = acc;
    }
    __syncthreads();
    if (t < 32) {                       // qW = qvec @ Wdot
        float acc = 0.0f;
        for (int e = 0; e < 32; ++e) acc += qv[e] * Wdot[e * 32 + t];
        qv[32 + t] = acc;
    }

    int n = blockIdx.x * 256 + t;
    bool act = n < NN;
    float z = 0.0f; int b = 0;          // ONLY these live across grid barriers
    float f[32];
    if (act) {
        z = pos[3 * n + 2];
        b = batch[n];
        const float4* nf4 = (const float4*)nf;
        float4* Lf4 = (float4*)Lf;
        #pragma unroll
        for (int j = 0; j < 8; ++j) {
            float4 v = nf4[n * 8 + j];
            f[4*j] = v.x; f[4*j+1] = v.y; f[4*j+2] = v.z; f[4*j+3] = v.w;
            Lf4[t * 9 + j] = v;
        }
        atomicMax(&zl[b], fencode(-z));   // max fencode(-z) = fencode(-zmin)
        atomicMax(&zh[b], fencode(z));    // max fencode(z)  = fencode(zmax)
        Lb[t] = b;
    } else {
        #pragma unroll
        for (int j = 0; j < 32; ++j) f[j] = 0.0f;
        Lb[t] = -1;
    }
    __syncthreads();                    // qv[32..], zl/zh block-partials ready
    {   // Pk[h][d] = sum_e W2_kd[h,d*32+e] * qW[e]
        int h = t >> 5, d = t & 31;
        float acc = 0.0f;
        for (int e = 0; e < 32; ++e) acc += W2_kd[h * 1024 + d * 32 + e] * qv[32 + e];
        Pk[t] = acc;
    }
    for (int i = t; i < 1024; i += 256) {   // Wc = Wq_graph @ Wdot
        int d = i >> 5, e = i & 31;
        float acc = 0.0f;
        for (int m = 0; m < 32; ++m) acc += Wq_graph[d * 32 + m] * Wdot[m * 32 + e];
        Wc[i] = acc;
    }
    if (t < 16) {                       // publish partials, reset for reuse
        wsu[WS_PZM + t * 128 + blockIdx.x] = zl[t];
        wsu[WS_PZX + t * 128 + blockIdx.x] = zh[t];
        zl[t] = 0u; zh[t] = 0u;
    }
    {   // zero ZSUM + T  (8224 floats grid-wide)
        int g = blockIdx.x * 256 + t;
        if (g < 8224) ws[WS_ZSUM + g] = 0.0f;
    }
    __syncthreads();                    // Pk ready for u
    float u[8];                         // u[h] = f . Pk[h,:]  (f dies after)
    #pragma unroll
    for (int h = 0; h < 8; ++h) {
        float acc = 0.0f;
        #pragma unroll
        for (int d = 0; d < 32; ++d) acc += f[d] * Pk[h * 32 + d];
        u[h] = acc;
    }
    gbarrier(barc, NBLK);               // ---- partials + zeroed T everywhere

    // ====== step A: z-reduce, edges, kd/vd MLPs, zsum, T-reduce ===========
    {   // reduce NBLK partials per batch: thread t -> (batch t>>4, chunk t&15)
        int b4 = t >> 4, c = t & 15;
        unsigned m0 = 0u, m1 = 0u;
        int i0 = c * 8, i1 = i0 + 8; if (i1 > NBLK) i1 = NBLK;
        for (int i = i0; i < i1; ++i) {
            unsigned p0 = wsu[WS_PZM + b4 * 128 + i];
            unsigned p1 = wsu[WS_PZX + b4 * 128 + i];
            m0 = m0 > p0 ? m0 : p0;
            m1 = m1 > p1 ? m1 : p1;
        }
        atomicMax(&zl[b4], m0);
        atomicMax(&zh[b4], m1);
    }
    __syncthreads();
    {
        float zmin = -fdecode(zl[b]);
        float zmax =  fdecode(zh[b]);
        float xl[2];
        xl[0] = z - zmin + DIST_C;
        xl[1] = zmax + DIST_C - z;
        #pragma unroll
        for (int s = 0; s < 2; ++s) {
            float inv = 1.0f / (xl[s] + EPS_C);
            float edge[8];
            #pragma unroll
            for (int k = 0; k < 8; ++k) edge[k] = sinf(bwl[k] * xl[s]) * inv;
            float sacc = 0.0f;
            #pragma unroll
            for (int h = 0; h < 8; ++h) {
                float pkd = 0.0f, pvd = 0.0f;
                #pragma unroll
                for (int k = 0; k < 8; ++k) {
                    pkd += edge[k] * W1kd[k * 8 + h];
                    pvd += edge[k] * W1vd[k * 8 + h];
                }
                sacc += silu(pkd) * u[h];
                Lw[t * LWS + s * 8 + h] = silu(pvd);
            }
            float ev = act ? expf(sacc * SCALE_C) : 0.0f;
            if (act) atomicAdd(&zsl[b * 2 + s], ev);
            #pragma unroll
            for (int h = 0; h < 8; ++h) Lw[t * LWS + s * 8 + h] *= ev;
        }
    }
    __syncthreads();                    // Lw, zsl complete
    if (t < 32 && zsl[t] != 0.0f) atomicAdd(&ws[WS_ZSUM + t], zsl[t]);

    {   // segment outer-product reduce: T[b] += W^T(16 x n) @ F(n x 32)
        int base = blockIdx.x * 256;
        int count = NN - base; if (count > 256) count = 256;
        int bf = Lb[0], bl = Lb[count - 1];
        int wave = t >> 6, lane = t & 63;
        int sh = lane & 15;
        int dg = lane >> 4;
        int i0 = wave * 64;
        int i1 = i0 + 64; if (i1 > count) i1 = count;
        const float4* Lf4r = (const float4*)Lf;
        for (int b2 = bf; b2 <= bl; ++b2) {
            float a0=0.f,a1=0.f,a2=0.f,a3=0.f,a4=0.f,a5=0.f,a6=0.f,a7=0.f;
            for (int i = i0; i < i1; ++i) {
                if (Lb[i] != b2) continue;
                float w = Lw[i * LWS + sh];
                float4 x0 = Lf4r[i * 9 + 2 * dg];
                float4 x1 = Lf4r[i * 9 + 2 * dg + 1];
                a0 += w * x0.x; a1 += w * x0.y; a2 += w * x0.z; a3 += w * x0.w;
                a4 += w * x1.x; a5 += w * x1.y; a6 += w * x1.z; a7 += w * x1.w;
            }
            float* Tb = ws + WS_T + b2 * 512 + sh * 32 + dg * 8;
            atomicAdd(&Tb[0], a0); atomicAdd(&Tb[1], a1);
            atomicAdd(&Tb[2], a2); atomicAdd(&Tb[3], a3);
            atomicAdd(&Tb[4], a4); atomicAdd(&Tb[5], a5);
            atomicAdd(&Tb[6], a6); atomicAdd(&Tb[7], a7);
        }
    }
    gbarrier(barc, 2 * NBLK);           // ---- T, zsum final everywhere ----

    // ====== step B: blocks 0..31 build dummy_new, A_kg, A_vg (Lw scratch) ==
    if (blockIdx.x < 32) {
        int b3 = blockIdx.x >> 1, s3 = blockIdx.x & 1;
        float* Tl = Lw;                 // Lw is dead; Lf must survive!
        float* dn = Lw + 320;
        Tl[t] = ws[WS_T + b3 * 512 + s3 * 256 + t];
        __syncthreads();
        if (t < 32) {
            float acc = 0.0f;
            #pragma unroll
            for (int h = 0; h < 8; ++h)
                #pragma unroll
                for (int d = 0; d < 32; ++d)
                    acc += Tl[h * 32 + d] * W2_vd[h * 1024 + d * 32 + t];
            float zs = ws[WS_ZSUM + b3 * 2 + s3];
            dn[t] = init_dummy[t] + acc / zs;
        }
        __syncthreads();
        {
            int h = t >> 5, e = t & 31;
            float ak = 0.0f, av = 0.0f;
            #pragma unroll
            for (int d = 0; d < 32; ++d) {
                float dv = dn[d];
                ak += dv * W2_kg[h * 1024 + d * 32 + e];
                av += dv * W2_vg[h * 1024 + d * 32 + e];
            }
            ws[WS_AKG + b3 * 512 + s3 * 256 + t] = ak;
            ws[WS_AVG + b3 * 512 + s3 * 256 + t] = av;
        }
    }
    gbarrier(barc, 3 * NBLK);           // ---- A_kg / A_vg visible ----

    // ====== step C: finale (recompute edges/akg/avgg/q4 — no spills) ======
    if (act) {
        // recompute edge features from z + persistent zl/zh
        float zmin = -fdecode(zl[b]);
        float zmax =  fdecode(zh[b]);
        float xl[2];
        xl[0] = z - zmin + DIST_C;
        xl[1] = zmax + DIST_C - z;
        float akg[2][8], avgg[2][8];
        #pragma unroll
        for (int s = 0; s < 2; ++s) {
            float inv = 1.0f / (xl[s] + EPS_C);
            float edge[8];
            #pragma unroll
            for (int k = 0; k < 8; ++k) edge[k] = sinf(bwl[k] * xl[s]) * inv;
            #pragma unroll
            for (int h = 0; h < 8; ++h) {
                float pkg = 0.0f, pvg = 0.0f;
                #pragma unroll
                for (int k = 0; k < 8; ++k) {
                    pkg += edge[k] * W1kg[k * 8 + h];
                    pvg += edge[k] * W1vg[k * 8 + h];
                }
                akg[s][h] = silu(pkg);
                avgg[s][h] = silu(pvg);
            }
        }
        // reload f from LDS, q4 = f @ Wc
        const float4* Lf4r = (const float4*)Lf;
        float4 fv4[8];
        #pragma unroll
        for (int j = 0; j < 8; ++j) fv4[j] = Lf4r[t * 9 + j];
        float4 q4[8];
        #pragma unroll
        for (int j = 0; j < 8; ++j) { q4[j].x = q4[j].y = q4[j].z = q4[j].w = 0.0f; }
        const float4* Wc4 = (const float4*)Wc;
        #pragma unroll
        for (int jj = 0; jj < 8; ++jj) {
            float fq[4] = { fv4[jj].x, fv4[jj].y, fv4[jj].z, fv4[jj].w };
            #pragma unroll
            for (int r = 0; r < 4; ++r) {
                float fd = fq[r];
                int d = jj * 4 + r;
                #pragma unroll
                for (int j = 0; j < 8; ++j) {
                    float4 w = Wc4[d * 8 + j];
                    q4[j].x += fd * w.x; q4[j].y += fd * w.y;
                    q4[j].z += fd * w.z; q4[j].w += fd * w.w;
                }
            }
        }
        const float4* Ak4 = (const float4*)(ws + WS_AKG);
        const float4* Av4 = (const float4*)(ws + WS_AVG);
        float sg[2];
        #pragma unroll
        for (int s = 0; s < 2; ++s) {
            float acc = 0.0f;
            #pragma unroll
            for (int h = 0; h < 8; ++h) {
                int rb = b * 128 + s * 64 + h * 8;
                float dotv = 0.0f;
                #pragma unroll
                for (int j = 0; j < 8; ++j) {
                    float4 a = Ak4[rb + j];
                    dotv += q4[j].x * a.x + q4[j].y * a.y + q4[j].z * a.z + q4[j].w * a.w;
                }
                acc += akg[s][h] * dotv;
            }
            sg[s] = acc * SCALE_C;
        }
        float mm = fmaxf(sg[0], sg[1]);
        float e0 = expf(sg[0] - mm), e1 = expf(sg[1] - mm);
        float inv = 1.0f / (e0 + e1);
        float ag0 = e0 * inv, ag1 = e1 * inv;
        float4 x4[8];
        #pragma unroll
        for (int j = 0; j < 8; ++j) x4[j] = fv4[j];
        #pragma unroll
        for (int s = 0; s < 2; ++s) {
            float ags = (s == 0) ? ag0 : ag1;
            #pragma unroll
            for (int h = 0; h < 8; ++h) {
                float wv = ags * avgg[s][h];
                int rb = b * 128 + s * 64 + h * 8;
                #pragma unroll
                for (int j = 0; j < 8; ++j) {
                    float4 a = Av4[rb + j];
                    x4[j].x += wv * a.x; x4[j].y += wv * a.y;
                    x4[j].z += wv * a.z; x4[j].w += wv * a.w;
                }
            }
        }
        float4* out4 = (float4*)out;
        #pragma unroll
        for (int j = 0; j < 8; ++j) out4[n * 8 + j] = x4[j];
    }
}

extern "C" void kernel_launch(void* const* d_in, const int* in_sizes, int n_in,
                              void* d_out, int out_size, void* d_ws, size_t ws_size,
                              hipStream_t stream) {
    const float* pos        = (const float*)d_in[0];
    const float* nf         = (const float*)d_in[1];
    const int*   batch      = (const int*)d_in[2];
    const float* bw         = (const float*)d_in[3];
    const float* init_dummy = (const float*)d_in[4];
    const float* Wq_dummy   = (const float*)d_in[5];
    const float* Wq_graph   = (const float*)d_in[6];
    const float* Wdot       = (const float*)d_in[7];
    const float* W1_kd      = (const float*)d_in[8];
    const float* W2_kd      = (const float*)d_in[9];
    const float* W1_vd      = (const float*)d_in[10];
    const float* W2_vd      = (const float*)d_in[11];
    const float* W1_kg      = (const float*)d_in[12];
    const float* W2_kg      = (const float*)d_in[13];
    const float* W1_vg      = (const float*)d_in[14];
    const float* W2_vg      = (const float*)d_in[15];
    float* ws  = (float*)d_ws;
    float* out = (float*)d_out;

    // zero the barrier counter (everything else is initialized in-kernel)
    hipMemsetAsync(d_ws, 0x00, 32, stream);

    hipLaunchKernelGGL(k_fused, dim3(NBLK), dim3(256), 0, stream,
                       pos, batch, nf, bw, init_dummy, Wq_dummy, Wq_graph,
                       Wdot, W1_kd, W2_kd, W1_vd, W2_vd, W1_kg, W2_kg,
                       W1_vg, W2_vg, ws, out);
}

// Round 6
// 160.488 us; speedup vs baseline: 2.6223x; 1.0041x over previous
//
#include <hip/hip_runtime.h>
#include <math.h>

#define NN 30000
#define NBLK 118
#define DIST_C 5.0f
#define EPS_C 1e-6f
#define SCALE_C 0.17677669529663687f  // 1/sqrt(32)

// workspace layout (float offsets)
#define WS_BAR  0      // 8 uints: [0] = monotonic barrier counter (memset 0)
#define WS_PZM  8      // 16*128 uints [b*128+blk]: per-block max(fencode(-z))
#define WS_PZX  2056   // 16*128 uints [b*128+blk]: per-block max(fencode(z))
#define WS_ZSUM 4104   // 32 f [b*2+s]          (zeroed in-kernel, sc1)
#define WS_T    4136   // 8192 f [b*512+(s*8+h)*32+d] (zeroed in-kernel, sc1)

// LDS row strides
#define LWS 17         // Lw: 17 floats/row (bank-safe)
#define LFS 34         // Lf: 34 floats/row = 17 float2 (8B-aligned, bank-safe)

__device__ __forceinline__ unsigned fencode(float f) {
    unsigned u = __float_as_uint(f);
    return (u & 0x80000000u) ? ~u : (u | 0x80000000u);
}
__device__ __forceinline__ float fdecode(unsigned c) {
    return __uint_as_float((c & 0x80000000u) ? (c ^ 0x80000000u) : ~c);
}
__device__ __forceinline__ float silu(float x) { return x / (1.0f + expf(-x)); }

// agent-scope (sc1) relaxed stores: globally visible once vmcnt drains
// (__syncthreads emits s_waitcnt vmcnt(0) before s_barrier).
__device__ __forceinline__ void gstoref(float* p, float v) {
    __hip_atomic_store(p, v, __ATOMIC_RELAXED, __HIP_MEMORY_SCOPE_AGENT);
}
__device__ __forceinline__ void gstoreu(unsigned* p, unsigned v) {
    __hip_atomic_store(p, v, __ATOMIC_RELAXED, __HIP_MEMORY_SCOPE_AGENT);
}

// Grid barrier WITHOUT __threadfence: all cross-block data is written with
// sc1 ops (atomicAdd / gstore*), drained by the leading __syncthreads, so no
// L2 writeback (buffer_wbl2) is needed. Acquire poll invalidates caches on
// exit. All NBLK blocks co-resident (118 blocks <= 256 CUs) -> no deadlock.
__device__ __forceinline__ void gbarrier(unsigned* cnt, unsigned target) {
    __syncthreads();
    if (threadIdx.x == 0) {
        __hip_atomic_fetch_add(cnt, 1u, __ATOMIC_RELAXED, __HIP_MEMORY_SCOPE_AGENT);
        while (__hip_atomic_load(cnt, __ATOMIC_ACQUIRE, __HIP_MEMORY_SCOPE_AGENT) < target) {
            __builtin_amdgcn_s_sleep(1);
        }
    }
    __syncthreads();
}

__global__ __launch_bounds__(256) void k_fused(
    const float* __restrict__ pos, const int* __restrict__ batch,
    const float* __restrict__ nf, const float* __restrict__ bw,
    const float* __restrict__ init_dummy, const float* __restrict__ Wq_dummy,
    const float* __restrict__ Wq_graph, const float* __restrict__ Wdot,
    const float* __restrict__ W1_kd, const float* __restrict__ W2_kd,
    const float* __restrict__ W1_vd, const float* __restrict__ W2_vd,
    const float* __restrict__ W1_kg, const float* __restrict__ W2_kg,
    const float* __restrict__ W1_vg, const float* __restrict__ W2_vg,
    float* __restrict__ ws, float* __restrict__ out)
{
    __shared__ float Lf[256 * LFS];     // node features: step 0 -> step C
    __shared__ float Lw[256 * LWS];     // step A weights; step B scratch
    __shared__ float Akg[4 * 256];      // per-block A matrices (<=4 pairs)
    __shared__ float Avg[4 * 256];
    __shared__ int   Lb[256];
    __shared__ float W1kd[64], W1vd[64], W1kg[64], W1vg[64];
    __shared__ float Pk[256], qv[64], zsl[32], bwl[8];
    __shared__ unsigned zl[16], zh[16]; // persists to step C

    int t = threadIdx.x;
    unsigned* wsu = (unsigned*)ws;
    unsigned* barc = wsu + WS_BAR;

    // ====== step 0: staging, precompute, z partials, zero T, u = f.Pk ======
    if (t < 64) { W1kd[t] = W1_kd[t]; W1vd[t] = W1_vd[t];
                  W1kg[t] = W1_kg[t]; W1vg[t] = W1_vg[t]; }
    if (t < 8)  bwl[t] = bw[t];
    if (t < 16) { zl[t] = 0u; zh[t] = 0u; }
    if (t < 32) zsl[t] = 0.0f;
    if (t < 32) {                       // qvec = init_dummy @ Wq_dummy
        float acc = 0.0f;
        for (int d = 0; d < 32; ++d) acc += init_dummy[d] * Wq_dummy[d * 32 + t];
        qv[t] = acc;
    }
    __syncthreads();
    if (t < 32) {                       // qW = qvec @ Wdot
        float acc = 0.0f;
        for (int e = 0; e < 32; ++e) acc += qv[e] * Wdot[e * 32 + t];
        qv[32 + t] = acc;
    }

    int n = blockIdx.x * 256 + t;
    bool act = n < NN;
    float z = 0.0f; int b = 0;          // only these + u[8] live across barriers
    float f[32];
    if (act) {
        z = pos[3 * n + 2];
        b = batch[n];
        const float4* nf4 = (const float4*)nf;
        float2* Lf2 = (float2*)Lf;
        #pragma unroll
        for (int j = 0; j < 8; ++j) {
            float4 v = nf4[n * 8 + j];
            f[4*j] = v.x; f[4*j+1] = v.y; f[4*j+2] = v.z; f[4*j+3] = v.w;
            Lf2[t * 17 + 2*j]     = make_float2(v.x, v.y);
            Lf2[t * 17 + 2*j + 1] = make_float2(v.z, v.w);
        }
        atomicMax(&zl[b], fencode(-z));
        atomicMax(&zh[b], fencode(z));
        Lb[t] = b;
    } else {
        #pragma unroll
        for (int j = 0; j < 32; ++j) f[j] = 0.0f;
        Lb[t] = -1;
    }
    __syncthreads();                    // qv[32..], zl/zh block-partials ready
    {   // Pk[h][d] = sum_e W2_kd[h,d*32+e] * qW[e]
        int h = t >> 5, d = t & 31;
        float acc = 0.0f;
        for (int e = 0; e < 32; ++e) acc += W2_kd[h * 1024 + d * 32 + e] * qv[32 + e];
        Pk[t] = acc;
    }
    if (t < 16) {                       // publish partials (sc1), reset for reuse
        gstoreu(&wsu[WS_PZM + t * 128 + blockIdx.x], zl[t]);
        gstoreu(&wsu[WS_PZX + t * 128 + blockIdx.x], zh[t]);
        zl[t] = 0u; zh[t] = 0u;
    }
    {   // zero ZSUM + T  (8224 floats grid-wide, sc1)
        int g = blockIdx.x * 256 + t;
        if (g < 8224) gstoref(&ws[WS_ZSUM + g], 0.0f);
    }
    __syncthreads();                    // Pk ready
    float u[8];                         // u[h] = f . Pk[h,:]
    #pragma unroll
    for (int h = 0; h < 8; ++h) {
        float acc = 0.0f;
        #pragma unroll
        for (int d = 0; d < 32; ++d) acc += f[d] * Pk[h * 32 + d];
        u[h] = acc;
    }
    gbarrier(barc, NBLK);               // ---- partials + zeroed T everywhere

    // ====== step A: z-reduce, edges, kd/vd MLPs, zsum, T-reduce ===========
    {   // reduce NBLK partials per batch
        int b4 = t >> 4, c = t & 15;
        unsigned m0 = 0u, m1 = 0u;
        int i0 = c * 8, i1 = i0 + 8; if (i1 > NBLK) i1 = NBLK;
        for (int i = i0; i < i1; ++i) {
            unsigned p0 = wsu[WS_PZM + b4 * 128 + i];
            unsigned p1 = wsu[WS_PZX + b4 * 128 + i];
            m0 = m0 > p0 ? m0 : p0;
            m1 = m1 > p1 ? m1 : p1;
        }
        atomicMax(&zl[b4], m0);
        atomicMax(&zh[b4], m1);
    }
    __syncthreads();
    {
        float zmin = -fdecode(zl[b]);
        float zmax =  fdecode(zh[b]);
        float xl[2];
        xl[0] = z - zmin + DIST_C;
        xl[1] = zmax + DIST_C - z;
        #pragma unroll
        for (int s = 0; s < 2; ++s) {
            float inv = 1.0f / (xl[s] + EPS_C);
            float edge[8];
            #pragma unroll
            for (int k = 0; k < 8; ++k) edge[k] = sinf(bwl[k] * xl[s]) * inv;
            float sacc = 0.0f;
            #pragma unroll
            for (int h = 0; h < 8; ++h) {
                float pkd = 0.0f, pvd = 0.0f;
                #pragma unroll
                for (int k = 0; k < 8; ++k) {
                    pkd += edge[k] * W1kd[k * 8 + h];
                    pvd += edge[k] * W1vd[k * 8 + h];
                }
                sacc += silu(pkd) * u[h];
                Lw[t * LWS + s * 8 + h] = silu(pvd);
            }
            float ev = act ? expf(sacc * SCALE_C) : 0.0f;
            if (act) atomicAdd(&zsl[b * 2 + s], ev);
            #pragma unroll
            for (int h = 0; h < 8; ++h) Lw[t * LWS + s * 8 + h] *= ev;
        }
    }
    __syncthreads();                    // Lw, zsl complete
    if (t < 32 && zsl[t] != 0.0f) atomicAdd(&ws[WS_ZSUM + t], zsl[t]);

    {   // segmented outer-product reduce: T[b] += W^T(16 x n) @ F(n x 32)
        int base = blockIdx.x * 256;
        int count = NN - base; if (count > 256) count = 256;
        int wave = t >> 6, lane = t & 63;
        int sh = lane & 15;
        int dg = lane >> 4;             // 0..3
        int i0 = wave * 64;
        int i1 = i0 + 64; if (i1 > count) i1 = count;
        if (i0 < count) {
            const float2* Lf2 = (const float2*)Lf;
            int cur = Lb[i0];
            float a0=0.f,a1=0.f,a2=0.f,a3=0.f,a4=0.f,a5=0.f,a6=0.f,a7=0.f;
            for (int i = i0; i < i1; ++i) {
                int bi = Lb[i];         // wave-uniform
                float w  = Lw[i * LWS + sh];
                float2 x0 = Lf2[i * 17 + 4*dg + 0];
                float2 x1 = Lf2[i * 17 + 4*dg + 1];
                float2 x2 = Lf2[i * 17 + 4*dg + 2];
                float2 x3 = Lf2[i * 17 + 4*dg + 3];
                if (bi != cur) {        // uniform flush on batch change
                    float* Tb = ws + WS_T + cur * 512 + sh * 32 + dg * 8;
                    atomicAdd(&Tb[0], a0); atomicAdd(&Tb[1], a1);
                    atomicAdd(&Tb[2], a2); atomicAdd(&Tb[3], a3);
                    atomicAdd(&Tb[4], a4); atomicAdd(&Tb[5], a5);
                    atomicAdd(&Tb[6], a6); atomicAdd(&Tb[7], a7);
                    a0=a1=a2=a3=a4=a5=a6=a7=0.f;
                    cur = bi;
                }
                a0 += w * x0.x; a1 += w * x0.y; a2 += w * x1.x; a3 += w * x1.y;
                a4 += w * x2.x; a5 += w * x2.y; a6 += w * x3.x; a7 += w * x3.y;
            }
            float* Tb = ws + WS_T + cur * 512 + sh * 32 + dg * 8;
            atomicAdd(&Tb[0], a0); atomicAdd(&Tb[1], a1);
            atomicAdd(&Tb[2], a2); atomicAdd(&Tb[3], a3);
            atomicAdd(&Tb[4], a4); atomicAdd(&Tb[5], a5);
            atomicAdd(&Tb[6], a6); atomicAdd(&Tb[7], a7);
        }
    }
    gbarrier(barc, 2 * NBLK);           // ---- T, zsum final everywhere ----

    // ====== step B: per-block dn + A_kg/A_vg for its own batches (LDS) ====
    int bf, nprs;
    {
        int base = blockIdx.x * 256;
        int count = NN - base; if (count > 256) count = 256;
        bf = Lb[0];
        int bl = Lb[count - 1];
        int nb = bl - bf + 1; if (nb > 2) nb = 2;   // sorted batch, span <= 2
        nprs = nb * 2;
        float* Tl   = Lw;               // Lw dead: reuse as scratch
        float* part = Lw + 256;
        float* dn   = Lw + 512;
        for (int p = 0; p < nprs; ++p) {
            int b3 = bf + (p >> 1), s3 = p & 1;
            Tl[t] = ws[WS_T + b3 * 512 + s3 * 256 + t];
            __syncthreads();
            {   // part[h*32+d3] = sum_d Tl[h*32+d] * W2_vd[h,d*32+d3]
                int h = t >> 5, d3 = t & 31;
                float acc = 0.0f;
                #pragma unroll
                for (int d = 0; d < 32; ++d)
                    acc += Tl[h * 32 + d] * W2_vd[h * 1024 + d * 32 + d3];
                part[t] = acc;
            }
            __syncthreads();
            if (t < 32) {
                float acc = 0.0f;
                #pragma unroll
                for (int h = 0; h < 8; ++h) acc += part[h * 32 + t];
                float zs = ws[WS_ZSUM + b3 * 2 + s3];
                dn[t] = init_dummy[t] + acc / zs;
            }
            __syncthreads();
            {   // A[h*32+e] = sum_d dn[d] * W2_*g[h,d*32+e]
                int h = t >> 5, e = t & 31;
                float ak = 0.0f, av = 0.0f;
                #pragma unroll
                for (int d = 0; d < 32; ++d) {
                    float dv = dn[d];
                    ak += dv * W2_kg[h * 1024 + d * 32 + e];
                    av += dv * W2_vg[h * 1024 + d * 32 + e];
                }
                Akg[p * 256 + t] = ak;
                Avg[p * 256 + t] = av;
            }
            __syncthreads();
        }
    }
    __syncthreads();                    // Akg/Avg visible block-wide

    // ====== step C: finale (A from LDS; q via L1-broadcast weights) =======
    if (act) {
        float zmin = -fdecode(zl[b]);
        float zmax =  fdecode(zh[b]);
        float xl[2];
        xl[0] = z - zmin + DIST_C;
        xl[1] = zmax + DIST_C - z;
        float akg[2][8], avgg[2][8];
        #pragma unroll
        for (int s = 0; s < 2; ++s) {
            float inv = 1.0f / (xl[s] + EPS_C);
            float edge[8];
            #pragma unroll
            for (int k = 0; k < 8; ++k) edge[k] = sinf(bwl[k] * xl[s]) * inv;
            #pragma unroll
            for (int h = 0; h < 8; ++h) {
                float pkg = 0.0f, pvg = 0.0f;
                #pragma unroll
                for (int k = 0; k < 8; ++k) {
                    pkg += edge[k] * W1kg[k * 8 + h];
                    pvg += edge[k] * W1vg[k * 8 + h];
                }
                akg[s][h] = silu(pkg);
                avgg[s][h] = silu(pvg);
            }
        }
        // reload f from LDS
        const float2* Lf2 = (const float2*)Lf;
        float fr[32];
        #pragma unroll
        for (int j = 0; j < 16; ++j) {
            float2 v = Lf2[t * 17 + j];
            fr[2*j] = v.x; fr[2*j+1] = v.y;
        }
        // qg = f @ Wq_graph  (weights L1-broadcast: all lanes same address)
        float4 qg4[8];
        #pragma unroll
        for (int j = 0; j < 8; ++j) { qg4[j].x=qg4[j].y=qg4[j].z=qg4[j].w=0.f; }
        const float4* Wg4 = (const float4*)Wq_graph;
        #pragma unroll
        for (int d = 0; d < 32; ++d) {
            float fd = fr[d];
            #pragma unroll
            for (int j = 0; j < 8; ++j) {
                float4 w = Wg4[d * 8 + j];
                qg4[j].x += fd*w.x; qg4[j].y += fd*w.y;
                qg4[j].z += fd*w.z; qg4[j].w += fd*w.w;
            }
        }
        float qg[32];
        #pragma unroll
        for (int j = 0; j < 8; ++j) {
            qg[4*j]=qg4[j].x; qg[4*j+1]=qg4[j].y; qg[4*j+2]=qg4[j].z; qg[4*j+3]=qg4[j].w;
        }
        // q4 = qg @ Wdot
        float4 q4[8];
        #pragma unroll
        for (int j = 0; j < 8; ++j) { q4[j].x=q4[j].y=q4[j].z=q4[j].w=0.f; }
        const float4* Wd4 = (const float4*)Wdot;
        #pragma unroll
        for (int e = 0; e < 32; ++e) {
            float fe = qg[e];
            #pragma unroll
            for (int j = 0; j < 8; ++j) {
                float4 w = Wd4[e * 8 + j];
                q4[j].x += fe*w.x; q4[j].y += fe*w.y;
                q4[j].z += fe*w.z; q4[j].w += fe*w.w;
            }
        }
        int slot = (b - bf) * 2;        // + s
        const float4* Ak4 = (const float4*)Akg;
        const float4* Av4 = (const float4*)Avg;
        float sg[2];
        #pragma unroll
        for (int s = 0; s < 2; ++s) {
            float acc = 0.0f;
            #pragma unroll
            for (int h = 0; h < 8; ++h) {
                int rb = (slot + s) * 64 + h * 8;
                float dotv = 0.0f;
                #pragma unroll
                for (int j = 0; j < 8; ++j) {
                    float4 a = Ak4[rb + j];
                    dotv += q4[j].x*a.x + q4[j].y*a.y + q4[j].z*a.z + q4[j].w*a.w;
                }
                acc += akg[s][h] * dotv;
            }
            sg[s] = acc * SCALE_C;
        }
        float mm = fmaxf(sg[0], sg[1]);
        float e0 = expf(sg[0] - mm), e1 = expf(sg[1] - mm);
        float inv = 1.0f / (e0 + e1);
        float ag0 = e0 * inv, ag1 = e1 * inv;
        float4 x4[8];
        #pragma unroll
        for (int j = 0; j < 8; ++j)
            x4[j] = make_float4(fr[4*j], fr[4*j+1], fr[4*j+2], fr[4*j+3]);
        #pragma unroll
        for (int s = 0; s < 2; ++s) {
            float ags = (s == 0) ? ag0 : ag1;
            #pragma unroll
            for (int h = 0; h < 8; ++h) {
                float wv = ags * avgg[s][h];
                int rb = (slot + s) * 64 + h * 8;
                #pragma unroll
                for (int j = 0; j < 8; ++j) {
                    float4 a = Av4[rb + j];
                    x4[j].x += wv*a.x; x4[j].y += wv*a.y;
                    x4[j].z += wv*a.z; x4[j].w += wv*a.w;
                }
            }
        }
        float4* out4 = (float4*)out;
        #pragma unroll
        for (int j = 0; j < 8; ++j) out4[n * 8 + j] = x4[j];
    }
}

extern "C" void kernel_launch(void* const* d_in, const int* in_sizes, int n_in,
                              void* d_out, int out_size, void* d_ws, size_t ws_size,
                              hipStream_t stream) {
    const float* pos        = (const float*)d_in[0];
    const float* nf         = (const float*)d_in[1];
    const int*   batch      = (const int*)d_in[2];
    const float* bw         = (const float*)d_in[3];
    const float* init_dummy = (const float*)d_in[4];
    const float* Wq_dummy   = (const float*)d_in[5];
    const float* Wq_graph   = (const float*)d_in[6];
    const float* Wdot       = (const float*)d_in[7];
    const float* W1_kd      = (const float*)d_in[8];
    const float* W2_kd      = (const float*)d_in[9];
    const float* W1_vd      = (const float*)d_in[10];
    const float* W2_vd      = (const float*)d_in[11];
    const float* W1_kg      = (const float*)d_in[12];
    const float* W2_kg      = (const float*)d_in[13];
    const float* W1_vg      = (const float*)d_in[14];
    const float* W2_vg      = (const float*)d_in[15];
    float* ws  = (float*)d_ws;
    float* out = (float*)d_out;

    // zero the barrier counter (everything else initialized in-kernel)
    hipMemsetAsync(d_ws, 0x00, 32, stream);

    hipLaunchKernelGGL(k_fused, dim3(NBLK), dim3(256), 0, stream,
                       pos, batch, nf, bw, init_dummy, Wq_dummy, Wq_graph,
                       Wdot, W1_kd, W2_kd, W1_vd, W2_vd, W1_kg, W2_kg,
                       W1_vg, W2_vg, ws, out);
}